// Round 1
// baseline (5241.940 us; speedup 1.0000x reference)
//
#include <hip/hip_runtime.h>
#include <math.h>
#include <stdint.h>
#include <stddef.h>

// Problem dims (hard-coded per reference)
#define B_ 512
#define H_ 512
#define E_ 512
#define V_ 2048
#define IN_ 1024
#define LSTEPS 32
#define LP1 33

// JAX threefry mode: 1 = partitionable (JAX >= 0.4.36 default), 0 = original
#define TF_PARTITIONABLE 1

__device__ __forceinline__ void tf2x32(uint32_t k0, uint32_t k1,
                                       uint32_t x0, uint32_t x1,
                                       uint32_t& o0, uint32_t& o1) {
  uint32_t ks2 = k0 ^ k1 ^ 0x1BD11BDAu;
  x0 += k0; x1 += k1;
#define TFR(R) { x0 += x1; x1 = (x1 << (R)) | (x1 >> (32 - (R))); x1 ^= x0; }
  TFR(13) TFR(15) TFR(26) TFR(6)
  x0 += k1; x1 += ks2 + 1u;
  TFR(17) TFR(29) TFR(16) TFR(24)
  x0 += ks2; x1 += k0 + 2u;
  TFR(13) TFR(15) TFR(26) TFR(6)
  x0 += k0; x1 += k1 + 3u;
  TFR(17) TFR(29) TFR(16) TFR(24)
  x0 += k1; x1 += ks2 + 4u;
  TFR(13) TFR(15) TFR(26) TFR(6)
  x0 += ks2; x1 += k0 + 5u;
#undef TFR
  o0 = x0; o1 = x1;
}

// Precompute the 32 per-step sample keys from key(1) = (0,1)
__global__ void init_keys_kernel(uint32_t* __restrict__ sk) {
  uint32_t k0 = 0u, k1 = 1u;
  for (int t = 0; t < LSTEPS; t++) {
    uint32_t a0, a1, b0, b1;
#if TF_PARTITIONABLE
    tf2x32(k0, k1, 0u, 0u, a0, a1);  // new key = words of ctr (0,0)
    tf2x32(k0, k1, 0u, 1u, b0, b1);  // sample key = words of ctr (0,1)
    sk[2 * t] = b0; sk[2 * t + 1] = b1;
    k0 = a0; k1 = a1;
#else
    tf2x32(k0, k1, 0u, 2u, a0, a1);  // pair (0,2)
    tf2x32(k0, k1, 1u, 3u, b0, b1);  // pair (1,3)
    // key = (w0(0,2), w0(1,3)); sk = (w1(0,2), w1(1,3))
    sk[2 * t] = a1; sk[2 * t + 1] = b1;
    k0 = a0; k1 = b0;
#endif
  }
}

// c = 0, e = broadcast(sos)
__global__ __launch_bounds__(256) void init_state_kernel(
    const float* __restrict__ sos, float* __restrict__ c, float* __restrict__ e) {
  int idx = blockIdx.x * 256 + threadIdx.x;
  if (idx < B_ * H_) {
    c[idx] = 0.0f;
    e[idx] = sos[idx & (E_ - 1)];
  }
}

// EOS column t=32: seq/logp/ent = 0, probs = 1
__global__ __launch_bounds__(256) void eos_fill_kernel(
    float* __restrict__ o_seq, float* __restrict__ o_probs,
    float* __restrict__ o_logp, float* __restrict__ o_ent) {
  int b = blockIdx.x, tid = threadIdx.x;
  float* pr = o_probs + ((size_t)b * LP1 + LSTEPS) * V_;
  for (int v = tid; v < V_; v += 256) pr[v] = 1.0f;
  if (tid == 0) {
    o_seq[b * LP1 + LSTEPS] = 0.0f;
    o_logp[b * LP1 + LSTEPS] = 0.0f;
    o_ent[b * LP1 + LSTEPS] = 0.0f;
  }
}

// Generic fp32 tiled GEMM: C[M,N] = A[M,K] @ B[K,N] + bias[N]
// BM=BN=64, BK=16, 256 threads, 4x4 micro-tile. grid = (M/64, N/64)
__global__ __launch_bounds__(256) void gemm_bias_kernel(
    const float* __restrict__ A, const float* __restrict__ Bm,
    const float* __restrict__ bias, float* __restrict__ C,
    int M, int N, int K) {
  __shared__ float As[16][64];
  __shared__ float Bs[16][64];
  int bm = blockIdx.x, bn = blockIdx.y;
  int tid = threadIdx.x;
  int tx = tid & 15, ty = tid >> 4;
  int arow = tid >> 2;           // 0..63
  int akc = (tid & 3) * 4;       // 0,4,8,12
  int brow = tid >> 4;           // 0..15
  int bcol = (tid & 15) * 4;     // 0..60
  const float* Ab = A + (size_t)(bm * 64) * K;
  const float* Bb = Bm + bn * 64;
  float acc[4][4] = {};
  for (int k0 = 0; k0 < K; k0 += 16) {
    float4 av = *(const float4*)(Ab + (size_t)arow * K + k0 + akc);
    float4 bv = *(const float4*)(Bb + (size_t)(k0 + brow) * N + bcol);
    __syncthreads();
    As[akc + 0][arow] = av.x; As[akc + 1][arow] = av.y;
    As[akc + 2][arow] = av.z; As[akc + 3][arow] = av.w;
    *(float4*)&Bs[brow][bcol] = bv;
    __syncthreads();
#pragma unroll
    for (int k = 0; k < 16; k++) {
      float4 a4 = *(const float4*)&As[k][ty * 4];
      float4 b4 = *(const float4*)&Bs[k][tx * 4];
      acc[0][0] += a4.x * b4.x; acc[0][1] += a4.x * b4.y; acc[0][2] += a4.x * b4.z; acc[0][3] += a4.x * b4.w;
      acc[1][0] += a4.y * b4.x; acc[1][1] += a4.y * b4.y; acc[1][2] += a4.y * b4.z; acc[1][3] += a4.y * b4.w;
      acc[2][0] += a4.z * b4.x; acc[2][1] += a4.z * b4.y; acc[2][2] += a4.z * b4.z; acc[2][3] += a4.z * b4.w;
      acc[3][0] += a4.w * b4.x; acc[3][1] += a4.w * b4.y; acc[3][2] += a4.w * b4.z; acc[3][3] += a4.w * b4.w;
    }
  }
  int crow0 = bm * 64 + ty * 4, ccol0 = bn * 64 + tx * 4;
  float4 b4 = *(const float4*)(bias + ccol0);
#pragma unroll
  for (int i = 0; i < 4; i++) {
    float4 o;
    o.x = acc[i][0] + b4.x; o.y = acc[i][1] + b4.y;
    o.z = acc[i][2] + b4.z; o.w = acc[i][3] + b4.w;
    *(float4*)(C + (size_t)(crow0 + i) * N + ccol0) = o;
  }
}

__device__ __forceinline__ float sigm(float x) { return 1.0f / (1.0f + expf(-x)); }

// Fused gates GEMM + LSTM cell.
// grid (16,16): blockIdx.x -> 32-wide hidden-col tile, blockIdx.y -> 32-row tile.
// Each block computes i,f,g,o tiles (cols j, 512+j, 1024+j, 1536+j) and applies the cell.
__global__ __launch_bounds__(256) void lstm_step_kernel(
    const float* __restrict__ e, const float* __restrict__ h_in,
    const float* __restrict__ w_ih, const float* __restrict__ w_hh,
    const float* __restrict__ b_ih, const float* __restrict__ b_hh,
    float* __restrict__ c, float* __restrict__ h_out) {
  __shared__ float As[16][32];
  __shared__ float Bs[4][16][32];
  int tid = threadIdx.x;
  int tx = tid & 15, ty = tid >> 4;
  int c0 = blockIdx.x * 32;
  int r0 = blockIdx.y * 32;
  float acc[4][2][2] = {};

  for (int kk = 0; kk < 64; kk++) {
    int kb = kk & 31;
    int k0 = kb * 16;
    const float* Asrc = (kk < 32) ? (e + (size_t)r0 * E_) : (h_in + (size_t)r0 * H_);
    const float* Wsrc = (kk < 32) ? w_ih : w_hh;
    // stage loads
    float4 av = make_float4(0.f, 0.f, 0.f, 0.f);
    if (tid < 128) {
      int row = tid >> 2, kc = (tid & 3) * 4;
      av = *(const float4*)(Asrc + (size_t)row * 512 + k0 + kc);
    }
    float4 bv[2];
#pragma unroll
    for (int i = 0; i < 2; i++) {
      int f = tid * 2 + i;
      int gate = f >> 7, kr = (f >> 3) & 15, nc = f & 7;
      bv[i] = *(const float4*)(Wsrc + (size_t)(k0 + kr) * (4 * H_) + gate * H_ + c0 + nc * 4);
    }
    __syncthreads();
    if (tid < 128) {
      int row = tid >> 2, kc = (tid & 3) * 4;
      As[kc + 0][row] = av.x; As[kc + 1][row] = av.y;
      As[kc + 2][row] = av.z; As[kc + 3][row] = av.w;
    }
#pragma unroll
    for (int i = 0; i < 2; i++) {
      int f = tid * 2 + i;
      int gate = f >> 7, kr = (f >> 3) & 15, nc = f & 7;
      *(float4*)&Bs[gate][kr][nc * 4] = bv[i];
    }
    __syncthreads();
#pragma unroll
    for (int k = 0; k < 16; k++) {
      float2 a = *(const float2*)&As[k][ty * 2];
#pragma unroll
      for (int g = 0; g < 4; g++) {
        float2 bb = *(const float2*)&Bs[g][k][tx * 2];
        acc[g][0][0] += a.x * bb.x; acc[g][0][1] += a.x * bb.y;
        acc[g][1][0] += a.y * bb.x; acc[g][1][1] += a.y * bb.y;
      }
    }
  }
  // epilogue: LSTM cell (torch gate order i,f,g,o)
#pragma unroll
  for (int i = 0; i < 2; i++) {
#pragma unroll
    for (int j = 0; j < 2; j++) {
      int r = r0 + ty * 2 + i;
      int col = c0 + tx * 2 + j;
      float ig = acc[0][i][j] + (b_ih[col] + b_hh[col]);
      float fg = acc[1][i][j] + (b_ih[H_ + col] + b_hh[H_ + col]);
      float gg = acc[2][i][j] + (b_ih[2 * H_ + col] + b_hh[2 * H_ + col]);
      float og = acc[3][i][j] + (b_ih[3 * H_ + col] + b_hh[3 * H_ + col]);
      size_t idx = (size_t)r * H_ + col;
      float cn = sigm(fg) * c[idx] + sigm(ig) * tanhf(gg);
      c[idx] = cn;
      h_out[idx] = sigm(og) * tanhf(cn);
    }
  }
}

// Per-row: log_softmax, entropy, probs write, threefry gumbel argmax sample,
// logp gather, embedding gather into e. One block per batch row.
__global__ __launch_bounds__(256) void sample_step_kernel(
    const float* __restrict__ z, const uint32_t* __restrict__ skv,
    const float* __restrict__ embedding, float* __restrict__ e,
    float* __restrict__ o_seq, float* __restrict__ o_probs,
    float* __restrict__ o_logp, float* __restrict__ o_ent, int t) {
  __shared__ float zs[V_];
  __shared__ float rmax[4], rsum[4], rps[4], rav[4];
  __shared__ int rai[4];
  int tid = threadIdx.x, b = blockIdx.x;
  int wid = tid >> 6;
  const float* zrow = z + (size_t)b * V_;
  float4 za = *(const float4*)(zrow + tid * 8);
  float4 zb = *(const float4*)(zrow + tid * 8 + 4);
  float zv[8] = {za.x, za.y, za.z, za.w, zb.x, zb.y, zb.z, zb.w};
  *(float4*)&zs[tid * 8] = za;
  *(float4*)&zs[tid * 8 + 4] = zb;

  // row max
  float m = zv[0];
#pragma unroll
  for (int i = 1; i < 8; i++) m = fmaxf(m, zv[i]);
  for (int off = 32; off; off >>= 1) m = fmaxf(m, __shfl_xor(m, off));
  if ((tid & 63) == 0) rmax[wid] = m;
  __syncthreads();
  m = fmaxf(fmaxf(rmax[0], rmax[1]), fmaxf(rmax[2], rmax[3]));

  // sum exp(z - m)
  float sh[8];
  float ssum = 0.f;
#pragma unroll
  for (int i = 0; i < 8; i++) { sh[i] = zv[i] - m; ssum += expf(sh[i]); }
  for (int off = 32; off; off >>= 1) ssum += __shfl_xor(ssum, off);
  if ((tid & 63) == 0) rsum[wid] = ssum;
  __syncthreads();
  float S = (rsum[0] + rsum[1]) + (rsum[2] + rsum[3]);
  float ls = logf(S);

  uint32_t sk0 = skv[2 * t], sk1 = skv[2 * t + 1];
  float psum = 0.f;
  float best = -INFINITY;
  int bi = 0;
  float pv[8];
#pragma unroll
  for (int i = 0; i < 8; i++) {
    float s = sh[i] - ls;            // matches jax log_softmax rounding
    float p = expf(s);
    pv[i] = p;
    psum += p * s;
    int v = tid * 8 + i;
    uint32_t o0, o1, bits;
#if TF_PARTITIONABLE
    uint32_t j = (uint32_t)(b * V_ + v);
    tf2x32(sk0, sk1, 0u, j, o0, o1);
    bits = o0 ^ o1;
#else
    uint32_t j = (uint32_t)(b * V_ + v);
    const uint32_t n2 = (uint32_t)(B_ * V_ / 2);
    if (j < n2) { tf2x32(sk0, sk1, j, j + n2, o0, o1); bits = o0; }
    else       { tf2x32(sk0, sk1, j - n2, j, o0, o1); bits = o1; }
#endif
    float f = __uint_as_float((bits >> 9) | 0x3f800000u) - 1.0f;
    float u = fmaxf(f, 1.17549435e-38f);
    float g = -logf(-logf(u));
    float a = s + g;
    if (a > best) { best = a; bi = v; }   // ascending v keeps lowest index on tie
  }
  // write probs
  float* pr = o_probs + ((size_t)b * LP1 + t) * V_ + tid * 8;
  float4 p0 = make_float4(pv[0], pv[1], pv[2], pv[3]);
  float4 p1 = make_float4(pv[4], pv[5], pv[6], pv[7]);
  *(float4*)pr = p0;
  *(float4*)(pr + 4) = p1;

  // reduce entropy partial and argmax
  for (int off = 32; off; off >>= 1) psum += __shfl_xor(psum, off);
  for (int off = 32; off; off >>= 1) {
    float ov = __shfl_xor(best, off);
    int oi = __shfl_xor(bi, off);
    if (ov > best || (ov == best && oi < bi)) { best = ov; bi = oi; }
  }
  if ((tid & 63) == 0) { rps[wid] = psum; rav[wid] = best; rai[wid] = bi; }
  __syncthreads();
  float ent = -((rps[0] + rps[1]) + (rps[2] + rps[3]));
  float bv2 = rav[0]; int sym = rai[0];
#pragma unroll
  for (int w2 = 1; w2 < 4; w2++) {
    if (rav[w2] > bv2 || (rav[w2] == bv2 && rai[w2] < sym)) { bv2 = rav[w2]; sym = rai[w2]; }
  }
  // gather next embedding
  const float* em = embedding + (size_t)sym * E_;
  for (int k2 = tid; k2 < E_; k2 += 256) e[(size_t)b * E_ + k2] = em[k2];
  if (tid == 0) {
    float s_sym = (zs[sym] - m) - ls;
    o_seq[b * LP1 + t] = (float)sym;
    o_logp[b * LP1 + t] = s_sym;
    o_ent[b * LP1 + t] = ent;
  }
}

extern "C" void kernel_launch(void* const* d_in, const int* in_sizes, int n_in,
                              void* d_out, int out_size, void* d_ws, size_t ws_size,
                              hipStream_t stream) {
  (void)in_sizes; (void)n_in; (void)out_size; (void)ws_size;
  const float* x     = (const float*)d_in[0];
  const float* agw   = (const float*)d_in[1];
  const float* agb   = (const float*)d_in[2];
  const float* sos   = (const float*)d_in[3];
  const float* emb   = (const float*)d_in[4];
  const float* w_ih  = (const float*)d_in[5];
  const float* w_hh  = (const float*)d_in[6];
  const float* b_ih  = (const float*)d_in[7];
  const float* b_hh  = (const float*)d_in[8];
  const float* out_w = (const float*)d_in[9];
  const float* out_b = (const float*)d_in[10];

  char* w = (char*)d_ws;
  uint32_t* sk = (uint32_t*)w;                                // 256 B used
  float* e  = (float*)(w + 1024);                             // 1 MB
  float* hA = (float*)(w + 1024 + 1 * 1048576);               // 1 MB
  float* hB = (float*)(w + 1024 + 2 * 1048576);               // 1 MB
  float* c  = (float*)(w + 1024 + 3 * 1048576);               // 1 MB
  float* z  = (float*)(w + 1024 + 4 * 1048576);               // 4 MB

  float* out = (float*)d_out;
  float* o_seq   = out;                                       // [512,33]
  float* o_probs = out + (size_t)B_ * LP1;                    // [512,33,2048]
  float* o_logp  = o_probs + (size_t)B_ * LP1 * V_;           // [512,33]
  float* o_ent   = o_logp + (size_t)B_ * LP1;                 // [512,33]

  init_keys_kernel<<<1, 1, 0, stream>>>(sk);
  init_state_kernel<<<(B_ * H_ + 255) / 256, 256, 0, stream>>>(sos, c, e);
  eos_fill_kernel<<<B_, 256, 0, stream>>>(o_seq, o_probs, o_logp, o_ent);
  // h0 = x @ agent_w + agent_b
  gemm_bias_kernel<<<dim3(B_ / 64, H_ / 64), 256, 0, stream>>>(x, agw, agb, hA, B_, H_, IN_);

  for (int t = 0; t < LSTEPS; t++) {
    float* hin  = (t & 1) ? hB : hA;
    float* hout = (t & 1) ? hA : hB;
    lstm_step_kernel<<<dim3(H_ / 32, B_ / 32), 256, 0, stream>>>(
        e, hin, w_ih, w_hh, b_ih, b_hh, c, hout);
    gemm_bias_kernel<<<dim3(B_ / 64, V_ / 64), 256, 0, stream>>>(
        hout, out_w, out_b, z, B_, V_, H_);
    sample_step_kernel<<<B_, 256, 0, stream>>>(
        z, sk, emb, e, o_seq, o_probs, o_logp, o_ent, t);
  }
}

// Round 2
// 2658.724 us; speedup vs baseline: 1.9716x; 1.9716x over previous
//
#include <hip/hip_runtime.h>
#include <math.h>
#include <stdint.h>
#include <stddef.h>

// Problem dims (hard-coded per reference)
#define B_ 512
#define H_ 512
#define E_ 512
#define V_ 2048
#define IN_ 1024
#define LSTEPS 32
#define LP1 33

// JAX threefry mode: 1 = partitionable (JAX >= 0.4.36 default), 0 = original
#define TF_PARTITIONABLE 1

// split-K factor for all GEMMs
#define SPLITK 4
#define PSTRIDE_GATES (B_ * 2048)      // 1048576 floats per partial (gates/logits)

__device__ __forceinline__ void tf2x32(uint32_t k0, uint32_t k1,
                                       uint32_t x0, uint32_t x1,
                                       uint32_t& o0, uint32_t& o1) {
  uint32_t ks2 = k0 ^ k1 ^ 0x1BD11BDAu;
  x0 += k0; x1 += k1;
#define TFR(R) { x0 += x1; x1 = (x1 << (R)) | (x1 >> (32 - (R))); x1 ^= x0; }
  TFR(13) TFR(15) TFR(26) TFR(6)
  x0 += k1; x1 += ks2 + 1u;
  TFR(17) TFR(29) TFR(16) TFR(24)
  x0 += ks2; x1 += k0 + 2u;
  TFR(13) TFR(15) TFR(26) TFR(6)
  x0 += k0; x1 += k1 + 3u;
  TFR(17) TFR(29) TFR(16) TFR(24)
  x0 += k1; x1 += ks2 + 4u;
  TFR(13) TFR(15) TFR(26) TFR(6)
  x0 += ks2; x1 += k0 + 5u;
#undef TFR
  o0 = x0; o1 = x1;
}

__global__ void init_keys_kernel(uint32_t* __restrict__ sk) {
  uint32_t k0 = 0u, k1 = 1u;
  for (int t = 0; t < LSTEPS; t++) {
    uint32_t a0, a1, b0, b1;
#if TF_PARTITIONABLE
    tf2x32(k0, k1, 0u, 0u, a0, a1);
    tf2x32(k0, k1, 0u, 1u, b0, b1);
    sk[2 * t] = b0; sk[2 * t + 1] = b1;
    k0 = a0; k1 = a1;
#else
    tf2x32(k0, k1, 0u, 2u, a0, a1);
    tf2x32(k0, k1, 1u, 3u, b0, b1);
    sk[2 * t] = a1; sk[2 * t + 1] = b1;
    k0 = a0; k1 = b0;
#endif
  }
}

__global__ __launch_bounds__(256) void init_state_kernel(
    const float* __restrict__ sos, float* __restrict__ c, float* __restrict__ e) {
  int idx = blockIdx.x * 256 + threadIdx.x;
  if (idx < B_ * H_) {
    c[idx] = 0.0f;
    e[idx] = sos[idx & (E_ - 1)];
  }
}

__global__ __launch_bounds__(256) void eos_fill_kernel(
    float* __restrict__ o_seq, float* __restrict__ o_probs,
    float* __restrict__ o_logp, float* __restrict__ o_ent) {
  int b = blockIdx.x, tid = threadIdx.x;
  float* pr = o_probs + ((size_t)b * LP1 + LSTEPS) * V_;
  for (int v = tid; v < V_; v += 256) pr[v] = 1.0f;
  if (tid == 0) {
    o_seq[b * LP1 + LSTEPS] = 0.0f;
    o_logp[b * LP1 + LSTEPS] = 0.0f;
    o_ent[b * LP1 + LSTEPS] = 0.0f;
  }
}

// ---- async global->LDS staging helper (16B per lane, wave-uniform LDS base)
typedef __attribute__((address_space(1))) const void GASV;
typedef __attribute__((address_space(3))) void LASV;
__device__ __forceinline__ void gld16(const void* g, void* l) {
  __builtin_amdgcn_global_load_lds((GASV*)g, (LASV*)l, 16, 0, 0);
}

// Split-K fp32 GEMM: P[z][128-row tile, 128-col tile] = A[:, kz..kz+KPB) @ B[kz.., :]
// A source: rows m, cols k. k < kHalf -> A0 (stride strideA), else A1 (k-kHalf).
// B source: row k of B0 / B1 (stride N). grid = (M/128, N/128, SPLITK).
// 256 threads, 8x8 micro-tile, double-buffered LDS, all staging via global_load_lds.
__global__ __launch_bounds__(256, 1) void gemm_splitk_kernel(
    const float* __restrict__ A0, const float* __restrict__ A1, int strideA,
    const float* __restrict__ B0, const float* __restrict__ B1,
    int N, int kHalf, int KPB, float* __restrict__ P, int pstride) {
  __shared__ float lds[2][4096];   // per buf: As[128][16] (2048 fl) + Bs[16][128] (2048 fl)
  int tid = threadIdx.x;
  int m0 = blockIdx.x * 128, n0 = blockIdx.y * 128;
  int k0 = blockIdx.z * KPB;
  // blocks never straddle kHalf (KPB divides kHalf in all our uses)
  bool hi = (k0 >= kHalf);
  const float* Ap = hi ? A1 : A0;
  const float* Bp = hi ? B1 : B0;
  int kb = hi ? (k0 - kHalf) : k0;

  int w = tid >> 6, l = tid & 63;
  // A staging: instr j covers As rows [(w*2+j)*16, +16); lane l -> row +l/4, k (l%4)*4
  int arow0 = (w * 2 + 0) * 16 + (l >> 2);
  int arow1 = (w * 2 + 1) * 16 + (l >> 2);
  int akc = (l & 3) * 4;
  // B staging: instr j covers Bs k-rows [(w*2+j)*2, +2); lane l -> row +l/32, col (l%32)*4
  int bk0 = (w * 2 + 0) * 2 + (l >> 5);
  int bk1 = (w * 2 + 1) * 2 + (l >> 5);
  int bcol = (l & 31) * 4;

  int ty = tid >> 4;       // 0..15  -> rows ty*4+i and 64+ty*4+i
  int tx = tid & 15;       // 0..15  -> cols tx*4+j and 64+tx*4+j

  float acc[8][8] = {};

  int nch = KPB >> 4;      // chunks of BK=16
#define STAGE(CH, TB) {                                                         \
    int kc = kb + ((CH) << 4);                                                  \
    gld16(Ap + (size_t)(m0 + arow0) * strideA + kc + akc,                       \
          (char*)&lds[TB][0] + (w * 2 + 0) * 1024);                             \
    gld16(Ap + (size_t)(m0 + arow1) * strideA + kc + akc,                       \
          (char*)&lds[TB][0] + (w * 2 + 1) * 1024);                             \
    gld16(Bp + (size_t)(kc + bk0) * N + n0 + bcol,                              \
          (char*)&lds[TB][2048] + (w * 2 + 0) * 1024);                          \
    gld16(Bp + (size_t)(kc + bk1) * N + n0 + bcol,                              \
          (char*)&lds[TB][2048] + (w * 2 + 1) * 1024);                          \
  }

  STAGE(0, 0)
  for (int ch = 0; ch < nch; ch++) {
    __syncthreads();                 // drains vmcnt -> buf[ch&1] ready
    if (ch + 1 < nch) STAGE(ch + 1, (ch + 1) & 1)
    const float* As = &lds[ch & 1][0];
    const float* Bs = &lds[ch & 1][2048];
#pragma unroll
    for (int kg = 0; kg < 4; kg++) {
      float4 a[8], b[8];
#pragma unroll
      for (int i = 0; i < 4; i++) {
        a[i]     = *(const float4*)&As[(ty * 4 + i) * 16 + kg * 4];
        a[i + 4] = *(const float4*)&As[(ty * 4 + i + 64) * 16 + kg * 4];
      }
#pragma unroll
      for (int kk = 0; kk < 4; kk++) {
        b[kk]     = *(const float4*)&Bs[(kg * 4 + kk) * 128 + tx * 4];
        b[kk + 4] = *(const float4*)&Bs[(kg * 4 + kk) * 128 + tx * 4 + 64];
      }
#pragma unroll
      for (int kk = 0; kk < 4; kk++) {
#pragma unroll
        for (int i = 0; i < 8; i++) {
          float av = ((const float*)&a[i])[kk];
#pragma unroll
          for (int j = 0; j < 4; j++) {
            acc[i][j]     += av * ((const float*)&b[kk])[j];
            acc[i][j + 4] += av * ((const float*)&b[kk + 4])[j];
          }
        }
      }
    }
  }
#undef STAGE

  float* Pb = P + (size_t)blockIdx.z * pstride;
#pragma unroll
  for (int i = 0; i < 8; i++) {
    int row = m0 + ((i < 4) ? (ty * 4 + i) : (64 + ty * 4 + i - 4));
#pragma unroll
    for (int jh = 0; jh < 2; jh++) {
      float4 o;
      o.x = acc[i][jh * 4 + 0]; o.y = acc[i][jh * 4 + 1];
      o.z = acc[i][jh * 4 + 2]; o.w = acc[i][jh * 4 + 3];
      *(float4*)&Pb[(size_t)row * N + n0 + tx * 4 + jh * 64] = o;
    }
  }
}

__device__ __forceinline__ float sigm(float x) { return 1.0f / (1.0f + expf(-x)); }

// Sum SPLITK gate partials + biases, apply LSTM cell. One float4 of H per thread.
__global__ __launch_bounds__(256) void cell_reduce_kernel(
    const float* __restrict__ P,
    const float* __restrict__ b_ih, const float* __restrict__ b_hh,
    float* __restrict__ c, float* __restrict__ h) {
  int idx = blockIdx.x * 256 + threadIdx.x;   // float4 index in [B, H] space
  int b = idx >> 7;
  int h4 = (idx & 127) * 4;
  float4 g4[4];
#pragma unroll
  for (int g = 0; g < 4; g++) {
    size_t off = (size_t)b * 2048 + g * 512 + h4;
    float4 s = *(const float4*)&P[off];
#pragma unroll
    for (int sgl = 1; sgl < SPLITK; sgl++) {
      float4 p = *(const float4*)&P[(size_t)sgl * PSTRIDE_GATES + off];
      s.x += p.x; s.y += p.y; s.z += p.z; s.w += p.w;
    }
    float4 bi = *(const float4*)&b_ih[g * 512 + h4];
    float4 bh = *(const float4*)&b_hh[g * 512 + h4];
    s.x += bi.x + bh.x; s.y += bi.y + bh.y; s.z += bi.z + bh.z; s.w += bi.w + bh.w;
    g4[g] = s;
  }
  size_t ci = (size_t)b * 512 + h4;
  float4 cold = *(const float4*)&c[ci];
  float4 cn, hn;
  {
    const float* ig = (const float*)&g4[0];
    const float* fg = (const float*)&g4[1];
    const float* gg = (const float*)&g4[2];
    const float* og = (const float*)&g4[3];
    float* cc = (float*)&cn; float* hh = (float*)&hn;
    const float* co = (const float*)&cold;
#pragma unroll
    for (int k = 0; k < 4; k++) {
      float cv = sigm(fg[k]) * co[k] + sigm(ig[k]) * tanhf(gg[k]);
      cc[k] = cv;
      hh[k] = sigm(og[k]) * tanhf(cv);
    }
  }
  *(float4*)&c[ci] = cn;
  *(float4*)&h[ci] = hn;
}

// Sum SPLITK partials + bias -> out (used once for h0). N = row width.
__global__ __launch_bounds__(256) void reduce_bias_kernel(
    const float* __restrict__ P, int pstride, const float* __restrict__ bias,
    float* __restrict__ out, int N, int total4) {
  int idx = blockIdx.x * 256 + threadIdx.x;
  if (idx >= total4) return;
  size_t off = (size_t)idx * 4;
  float4 s = *(const float4*)&P[off];
#pragma unroll
  for (int sgl = 1; sgl < SPLITK; sgl++) {
    float4 p = *(const float4*)&P[(size_t)sgl * pstride + off];
    s.x += p.x; s.y += p.y; s.z += p.z; s.w += p.w;
  }
  int col = (int)(off % N);
  float4 bv = *(const float4*)&bias[col];
  s.x += bv.x; s.y += bv.y; s.z += bv.z; s.w += bv.w;
  *(float4*)&out[off] = s;
}

// Per-row: reduce logits partials (+out_b), log_softmax, entropy, probs write,
// threefry gumbel argmax sample, logp gather, embedding gather. One block/row.
__global__ __launch_bounds__(256) void sample_step_kernel(
    const float* __restrict__ P, const float* __restrict__ out_b,
    const uint32_t* __restrict__ skv,
    const float* __restrict__ embedding, float* __restrict__ e,
    float* __restrict__ o_seq, float* __restrict__ o_probs,
    float* __restrict__ o_logp, float* __restrict__ o_ent, int t) {
  __shared__ float zs[V_];
  __shared__ float rmax[4], rsum[4], rps[4], rav[4];
  __shared__ int rai[4];
  int tid = threadIdx.x, b = blockIdx.x;
  int wid = tid >> 6;
  const float* pr0 = P + (size_t)b * V_ + tid * 8;
  float4 za = *(const float4*)pr0;
  float4 zb = *(const float4*)(pr0 + 4);
#pragma unroll
  for (int s = 1; s < SPLITK; s++) {
    float4 pa = *(const float4*)(pr0 + (size_t)s * PSTRIDE_GATES);
    float4 pb = *(const float4*)(pr0 + (size_t)s * PSTRIDE_GATES + 4);
    za.x += pa.x; za.y += pa.y; za.z += pa.z; za.w += pa.w;
    zb.x += pb.x; zb.y += pb.y; zb.z += pb.z; zb.w += pb.w;
  }
  {
    float4 oa = *(const float4*)(out_b + tid * 8);
    float4 ob = *(const float4*)(out_b + tid * 8 + 4);
    za.x += oa.x; za.y += oa.y; za.z += oa.z; za.w += oa.w;
    zb.x += ob.x; zb.y += ob.y; zb.z += ob.z; zb.w += ob.w;
  }
  float zv[8] = {za.x, za.y, za.z, za.w, zb.x, zb.y, zb.z, zb.w};
  *(float4*)&zs[tid * 8] = za;
  *(float4*)&zs[tid * 8 + 4] = zb;

  float m = zv[0];
#pragma unroll
  for (int i = 1; i < 8; i++) m = fmaxf(m, zv[i]);
  for (int off = 32; off; off >>= 1) m = fmaxf(m, __shfl_xor(m, off));
  if ((tid & 63) == 0) rmax[wid] = m;
  __syncthreads();
  m = fmaxf(fmaxf(rmax[0], rmax[1]), fmaxf(rmax[2], rmax[3]));

  float sh[8];
  float ssum = 0.f;
#pragma unroll
  for (int i = 0; i < 8; i++) { sh[i] = zv[i] - m; ssum += expf(sh[i]); }
  for (int off = 32; off; off >>= 1) ssum += __shfl_xor(ssum, off);
  if ((tid & 63) == 0) rsum[wid] = ssum;
  __syncthreads();
  float S = (rsum[0] + rsum[1]) + (rsum[2] + rsum[3]);
  float ls = logf(S);

  uint32_t sk0 = skv[2 * t], sk1 = skv[2 * t + 1];
  float psum = 0.f;
  float best = -INFINITY;
  int bi = 0;
  float pv[8];
#pragma unroll
  for (int i = 0; i < 8; i++) {
    float s = sh[i] - ls;
    float p = expf(s);
    pv[i] = p;
    psum += p * s;
    int v = tid * 8 + i;
    uint32_t o0, o1, bits;
#if TF_PARTITIONABLE
    uint32_t j = (uint32_t)(b * V_ + v);
    tf2x32(sk0, sk1, 0u, j, o0, o1);
    bits = o0 ^ o1;
#else
    uint32_t j = (uint32_t)(b * V_ + v);
    const uint32_t n2 = (uint32_t)(B_ * V_ / 2);
    if (j < n2) { tf2x32(sk0, sk1, j, j + n2, o0, o1); bits = o0; }
    else       { tf2x32(sk0, sk1, j - n2, j, o0, o1); bits = o1; }
#endif
    float f = __uint_as_float((bits >> 9) | 0x3f800000u) - 1.0f;
    float u = fmaxf(f, 1.17549435e-38f);
    float g = -logf(-logf(u));
    float a = s + g;
    if (a > best) { best = a; bi = v; }
  }
  float* prw = o_probs + ((size_t)b * LP1 + t) * V_ + tid * 8;
  *(float4*)prw = make_float4(pv[0], pv[1], pv[2], pv[3]);
  *(float4*)(prw + 4) = make_float4(pv[4], pv[5], pv[6], pv[7]);

  for (int off = 32; off; off >>= 1) psum += __shfl_xor(psum, off);
  for (int off = 32; off; off >>= 1) {
    float ov = __shfl_xor(best, off);
    int oi = __shfl_xor(bi, off);
    if (ov > best || (ov == best && oi < bi)) { best = ov; bi = oi; }
  }
  if ((tid & 63) == 0) { rps[wid] = psum; rav[wid] = best; rai[wid] = bi; }
  __syncthreads();
  float ent = -((rps[0] + rps[1]) + (rps[2] + rps[3]));
  float bv2 = rav[0]; int sym = rai[0];
#pragma unroll
  for (int w2 = 1; w2 < 4; w2++) {
    if (rav[w2] > bv2 || (rav[w2] == bv2 && rai[w2] < sym)) { bv2 = rav[w2]; sym = rai[w2]; }
  }
  const float* em = embedding + (size_t)sym * E_;
  for (int k2 = tid; k2 < E_; k2 += 256) e[(size_t)b * E_ + k2] = em[k2];
  if (tid == 0) {
    float s_sym = (zs[sym] - m) - ls;
    o_seq[b * LP1 + t] = (float)sym;
    o_logp[b * LP1 + t] = s_sym;
    o_ent[b * LP1 + t] = ent;
  }
}

extern "C" void kernel_launch(void* const* d_in, const int* in_sizes, int n_in,
                              void* d_out, int out_size, void* d_ws, size_t ws_size,
                              hipStream_t stream) {
  (void)in_sizes; (void)n_in; (void)out_size; (void)ws_size;
  const float* x     = (const float*)d_in[0];
  const float* agw   = (const float*)d_in[1];
  const float* agb   = (const float*)d_in[2];
  const float* sos   = (const float*)d_in[3];
  const float* emb   = (const float*)d_in[4];
  const float* w_ih  = (const float*)d_in[5];
  const float* w_hh  = (const float*)d_in[6];
  const float* b_ih  = (const float*)d_in[7];
  const float* b_hh  = (const float*)d_in[8];
  const float* out_w = (const float*)d_in[9];
  const float* out_b = (const float*)d_in[10];

  char* w = (char*)d_ws;
  uint32_t* sk = (uint32_t*)w;                                // 256 B used
  float* e  = (float*)(w + 1024);                             // 1 MB
  float* hA = (float*)(w + 1024 + 1 * 1048576);               // 1 MB
  float* hB = (float*)(w + 1024 + 2 * 1048576);               // 1 MB
  float* c  = (float*)(w + 1024 + 3 * 1048576);               // 1 MB
  float* P  = (float*)(w + 1024 + 4 * 1048576);               // 16 MB partials

  float* out = (float*)d_out;
  float* o_seq   = out;                                       // [512,33]
  float* o_probs = out + (size_t)B_ * LP1;                    // [512,33,2048]
  float* o_logp  = o_probs + (size_t)B_ * LP1 * V_;           // [512,33]
  float* o_ent   = o_logp + (size_t)B_ * LP1;                 // [512,33]

  const int BIG = 1 << 30;

  init_keys_kernel<<<1, 1, 0, stream>>>(sk);
  init_state_kernel<<<(B_ * H_ + 255) / 256, 256, 0, stream>>>(sos, c, e);
  eos_fill_kernel<<<B_, 256, 0, stream>>>(o_seq, o_probs, o_logp, o_ent);

  // h0 = x @ agent_w + agent_b   (M=512,N=512,K=1024; split-K 4, KPB=256)
  gemm_splitk_kernel<<<dim3(B_ / 128, H_ / 128, SPLITK), 256, 0, stream>>>(
      x, x, IN_, agw, agw, H_, BIG, IN_ / SPLITK, P, B_ * H_);
  reduce_bias_kernel<<<(B_ * H_ / 4 + 255) / 256, 256, 0, stream>>>(
      P, B_ * H_, agb, hA, H_, B_ * H_ / 4);

  for (int t = 0; t < LSTEPS; t++) {
    float* hin  = (t & 1) ? hB : hA;
    float* hout = (t & 1) ? hA : hB;
    // gates = [e|h] @ [w_ih; w_hh]  (K=1024, KPB=256, kHalf=512)
    gemm_splitk_kernel<<<dim3(B_ / 128, 2048 / 128, SPLITK), 256, 0, stream>>>(
        e, hin, E_, w_ih, w_hh, 4 * H_, E_, (E_ + H_) / SPLITK, P, PSTRIDE_GATES);
    cell_reduce_kernel<<<B_ * H_ / 4 / 256, 256, 0, stream>>>(P, b_ih, b_hh, c, hout);
    // logits partials = h @ out_w  (K=512, KPB=128)
    gemm_splitk_kernel<<<dim3(B_ / 128, V_ / 128, SPLITK), 256, 0, stream>>>(
        hout, hout, H_, out_w, out_w, V_, BIG, H_ / SPLITK, P, PSTRIDE_GATES);
    sample_step_kernel<<<B_, 256, 0, stream>>>(
        P, out_b, sk, emb, e, o_seq, o_probs, o_logp, o_ent, t);
  }
}